// Round 4
// baseline (1087.472 us; speedup 1.0000x reference)
//
#include <hip/hip_runtime.h>

#define D0 8192
#define D1 4096
#define D2 8192
#define NB 512  // blocks per matrix pass; also the split-K partial count

// ---------------------------------------------------------------------------
// Fused per-matrix pass. Block owns M/NB rows (register-resident), 512 thr.
//   e[j] = c[j] - tanh(W[j,:] . x)          (row dot, block reduce)
//   ACC: acc[cols] += e[j] * W[j,:]         (register slice, partial per block)
//   ERR: errsum += e[j]^2  -> atomicAdd(out)
// Rows processed in batches of R (W0:4, W1:2 => 8 float4/thread/batch) with
// ONE barrier per batch (parity LDS buffers), double-buffered batch loads.
// Batches/block = 4 in every instantiation.
// ---------------------------------------------------------------------------
template <int K, int M, bool ACC, bool ERR>
__device__ __forceinline__ void fused_body(
    const float* __restrict__ W, const float* __restrict__ x,
    const float* __restrict__ c, float* __restrict__ e,
    float* __restrict__ part, int bid, float* __restrict__ out) {
  constexpr int F4 = K / 2048;     // float4 chunks per thread per row (2 or 4)
  constexpr int R = 8 / F4;        // rows per batch (4 or 2)
  constexpr int RPB = M / NB;      // rows per block (16 or 8)
  static_assert(RPB / R == 4, "schedule below assumes 4 batches");

  const int t = threadIdx.x;
  const int lane = t & 63;
  const int wave = t >> 6;
  const int r0 = bid * RPB;

  __shared__ float red[2][R][8];

  float4 xr[F4];
#pragma unroll
  for (int i = 0; i < F4; ++i)
    xr[i] = *reinterpret_cast<const float4*>(&x[i * 2048 + t * 4]);

  float4 acc[F4];
#pragma unroll
  for (int i = 0; i < F4; ++i) acc[i] = make_float4(0.f, 0.f, 0.f, 0.f);

  float errsum = 0.f;
  float4 bufA[8], bufB[8];

  auto load = [&](float4* buf, int b) {
    const float* wp = W + (size_t)(r0 + b * R) * K;
#pragma unroll
    for (int r = 0; r < R; ++r)
#pragma unroll
      for (int i = 0; i < F4; ++i)
        buf[r * F4 + i] = *reinterpret_cast<const float4*>(
            &wp[(size_t)r * K + i * 2048 + t * 4]);
  };

  auto proc = [&](float4* buf, int b, int par) {
    const int j0 = r0 + b * R;
    float dp[R];
#pragma unroll
    for (int r = 0; r < R; ++r) {
      float s = 0.f;
#pragma unroll
      for (int i = 0; i < F4; ++i) {
        const float4 w = buf[r * F4 + i];
        s += w.x * xr[i].x + w.y * xr[i].y + w.z * xr[i].z + w.w * xr[i].w;
      }
      dp[r] = s;
    }
#pragma unroll
    for (int off = 32; off; off >>= 1) {
#pragma unroll
      for (int r = 0; r < R; ++r) dp[r] += __shfl_down(dp[r], off, 64);
    }
    if (lane == 0) {
#pragma unroll
      for (int r = 0; r < R; ++r) red[par][r][wave] = dp[r];
    }
    __syncthreads();
    float ej[R];
#pragma unroll
    for (int r = 0; r < R; ++r) {
      float s = red[par][r][0];
#pragma unroll
      for (int w = 1; w < 8; ++w) s += red[par][r][w];
      ej[r] = c[j0 + r] - tanhf(s);
    }
    if (t == 0) {
#pragma unroll
      for (int r = 0; r < R; ++r) e[j0 + r] = ej[r];
      if constexpr (ERR) {
#pragma unroll
        for (int r = 0; r < R; ++r) errsum += ej[r] * ej[r];
      }
    }
    if constexpr (ACC) {
#pragma unroll
      for (int r = 0; r < R; ++r)
#pragma unroll
        for (int i = 0; i < F4; ++i) {
          acc[i].x += ej[r] * buf[r * F4 + i].x;
          acc[i].y += ej[r] * buf[r * F4 + i].y;
          acc[i].z += ej[r] * buf[r * F4 + i].z;
          acc[i].w += ej[r] * buf[r * F4 + i].w;
        }
    }
  };

  // 4 batches, double-buffered; parity LDS => 1 barrier per batch, and a
  // wave can't overwrite a parity buffer until every wave passed the barrier
  // between the two uses.
  load(bufA, 0);
  load(bufB, 1);
  proc(bufA, 0, 0);
  load(bufA, 2);
  proc(bufB, 1, 1);
  load(bufB, 3);
  proc(bufA, 2, 0);
  proc(bufB, 3, 1);

  if constexpr (ACC) {
    float* pp = part + (size_t)bid * K;
#pragma unroll
    for (int i = 0; i < F4; ++i)
      *reinterpret_cast<float4*>(&pp[i * 2048 + t * 4]) = acc[i];
  }
  if constexpr (ERR) {
    if (t == 0) atomicAdd(out, errsum);
  }
}

// ---- step 1: W0 pass only (x1=x2=0 -> e0=x0 via tanh(0), e1=0, t2=0) ------
__global__ __launch_bounds__(512, 4) void pass_w0_kernel(
    const float* __restrict__ W0_, const float* __restrict__ x1_,
    const float* __restrict__ x0_, float* __restrict__ e0_,
    float* __restrict__ t1p_) {
  fused_body<D1, D0, true, false>(W0_, x1_, x0_, e0_, t1p_, blockIdx.x,
                                  nullptr);
}

// ---- full step: W0 pass (blocks 0..511) || W1 pass (blocks 512..1023) -----
__global__ __launch_bounds__(512, 4) void step_full_kernel(
    const float* __restrict__ W0_, const float* __restrict__ W1_,
    const float* __restrict__ x0_, const float* __restrict__ x1_,
    const float* __restrict__ x2_, float* __restrict__ e0_,
    float* __restrict__ e1_, float* __restrict__ t1p_,
    float* __restrict__ t2p_) {
  if (blockIdx.x < NB) {
    fused_body<D1, D0, true, false>(W0_, x1_, x0_, e0_, t1p_, blockIdx.x,
                                    nullptr);
  } else {
    fused_body<D2, D1, true, false>(W1_, x2_, x1_, e1_, t2p_, blockIdx.x - NB,
                                    nullptr);
  }
}

// ---- step 10: error-only passes for both matrices -------------------------
__global__ __launch_bounds__(512, 4) void step_err_kernel(
    const float* __restrict__ W0_, const float* __restrict__ W1_,
    const float* __restrict__ x0_, const float* __restrict__ x1_,
    const float* __restrict__ x2_, float* __restrict__ e0_,
    float* __restrict__ e1_, float* __restrict__ out) {
  if (blockIdx.x < NB) {
    fused_body<D1, D0, false, true>(W0_, x1_, x0_, e0_, nullptr, blockIdx.x,
                                    out);
  } else {
    fused_body<D2, D1, false, true>(W1_, x2_, x1_, e1_, nullptr,
                                    blockIdx.x - NB, out);
  }
}

// ---------------------------------------------------------------------------
// Update: reduce NB=512 partials (4 p-lanes x 128 deep + LDS combine) and
// apply x' = tanh(x + 0.01*clip(-e_self + t, -1, 1)).
// Block owns 64 consecutive elements of concat [t1(4096) | t2(8192)].
// grid 192 = full step; grid 64 = step-1 (t1 region only, x2 stays 0).
// ---------------------------------------------------------------------------
__global__ __launch_bounds__(256) void update_kernel(
    float* __restrict__ x1, const float* __restrict__ e1,
    const float* __restrict__ t1p, float* __restrict__ x2,
    const float* __restrict__ t2p) {
  const int t = threadIdx.x;
  const int cl = t & 63;
  const int pl = t >> 6;
  const int base = blockIdx.x * 64;
  __shared__ float red[4][64];
  float s = 0.f;
  if (base < D1) {
    const float* p = t1p + base + cl;
#pragma unroll 8
    for (int k = pl * 128; k < pl * 128 + 128; ++k) s += p[(size_t)k * D1];
  } else {
    const float* p = t2p + (base - D1) + cl;
#pragma unroll 8
    for (int k = pl * 128; k < pl * 128 + 128; ++k) s += p[(size_t)k * D2];
  }
  red[pl][cl] = s;
  __syncthreads();
  if (pl == 0) {
    const float ts = red[0][cl] + red[1][cl] + red[2][cl] + red[3][cl];
    if (base < D1) {
      const int i = base + cl;
      const float g = fminf(fmaxf(-e1[i] + ts, -1.f), 1.f);
      x1[i] = tanhf(x1[i] + 0.01f * g);
    } else {
      const int i = base - D1 + cl;
      const float g = fminf(fmaxf(-x2[i] + ts, -1.f), 1.f);
      x2[i] = tanhf(x2[i] + 0.01f * g);
    }
  }
}

// ---- init: x1=x2=0, e1=0, out=0 (ws/out arrive poisoned 0xAA) -------------
__global__ __launch_bounds__(256) void init_kernel(float* __restrict__ x1,
                                                   float* __restrict__ x2,
                                                   float* __restrict__ e1,
                                                   float* __restrict__ out) {
  int i = blockIdx.x * 256 + threadIdx.x;
  if (i == 0) out[0] = 0.f;
  if (i < D1) {
    x1[i] = 0.f;
    e1[i] = 0.f;
  }
  if (i < D2) x2[i] = 0.f;
}

// ---- sum(x^2) for the top layer (e2 = x2) ---------------------------------
__global__ __launch_bounds__(256) void sumsq_kernel(const float* __restrict__ x,
                                                    int n,
                                                    float* __restrict__ out) {
  float s = 0.f;
  for (int i = blockIdx.x * 256 + threadIdx.x; i < n; i += gridDim.x * 256)
    s += x[i] * x[i];
#pragma unroll
  for (int off = 32; off; off >>= 1) s += __shfl_down(s, off, 64);
  if ((threadIdx.x & 63) == 0) atomicAdd(out, s);
}

extern "C" void kernel_launch(void* const* d_in, const int* in_sizes, int n_in,
                              void* d_out, int out_size, void* d_ws,
                              size_t ws_size, hipStream_t stream) {
  const float* x0 = (const float*)d_in[0];  // 8192
  const float* W0 = (const float*)d_in[1];  // 8192x4096 row-major
  const float* W1 = (const float*)d_in[2];  // 4096x8192 row-major
  // d_in[3] = steps (fixed at 10; launch count must be static)
  float* out = (float*)d_out;

  float* ws = (float*)d_ws;
  float* x1 = ws;                      // 4096
  float* x2 = x1 + D1;                 // 8192
  float* e0 = x2 + D2;                 // 8192
  float* e1 = e0 + D0;                 // 4096
  float* t1p = e1 + D1;                // NB x 4096   (8 MB)
  float* t2p = t1p + (size_t)NB * D1;  // NB x 8192  (16 MB)

  const dim3 B512(512), B256(256);

  // init + step 1: x1=x2=0 => e0=x0 (tanh(0)=0 exact), e1=0, t2=0.
  // Only the W0 pass runs; update covers the t1 region only (x2 stays 0).
  init_kernel<<<D0 / 256, B256, 0, stream>>>(x1, x2, e1, out);
  pass_w0_kernel<<<NB, B512, 0, stream>>>(W0, x1, x0, e0, t1p);
  update_kernel<<<D1 / 64, B256, 0, stream>>>(x1, e1, t1p, x2, t2p);

  // steps 2..9: both matrix passes in ONE launch (independent halves),
  // each matrix read exactly once per step.
  for (int s = 2; s <= 9; ++s) {
    step_full_kernel<<<2 * NB, B512, 0, stream>>>(W0, W1, x0, x1, x2, e0, e1,
                                                  t1p, t2p);
    update_kernel<<<(D1 + D2) / 64, B256, 0, stream>>>(x1, e1, t1p, x2, t2p);
  }

  // step 10: only the errors are observable (final state update is dead).
  step_err_kernel<<<2 * NB, B512, 0, stream>>>(W0, W1, x0, x1, x2, e0, e1,
                                               out);
  sumsq_kernel<<<8, B256, 0, stream>>>(x2, D2, out);  // e2 = x2
}